// Round 5
// baseline (416.416 us; speedup 1.0000x reference)
//
#include <hip/hip_runtime.h>

constexpr int N_NODES = 100000;
constexpr int N_EDGES = 1600000;
constexpr int D = 32;
constexpr int NPB = 64;                             // nodes per bucket
constexpr int NBUK = (N_NODES + NPB - 1) / NPB;     // 1563 buckets
constexpr int NCHUNK = 32;                          // builder blocks = edge chunks
constexpr int EPC = N_EDGES / NCHUNK;               // 50000 edges per chunk (exact)
constexpr int SCAN_PAD = 1792;                      // 7*256 >= NBUK

// K1: per-chunk LDS histogram -> in-LDS exclusive scan -> scatter packed
// records into this block's OWN contiguous region (single-XCD line ownership).
// Record: e (21 bits) | node-local-id (6 bits) << 21.
__global__ __launch_bounds__(256) void build_kernel(
    const int4* __restrict__ dst4, int* __restrict__ records,
    int* __restrict__ bgstart, int* __restrict__ bgcnt)
{
    __shared__ int cnt_s[SCAN_PAD];
    __shared__ int cur_s[SCAN_PAD];
    __shared__ int wsum_s[4];
    const int k = blockIdx.x;                 // chunk id
    const int t = threadIdx.x;

    for (int i = t; i < SCAN_PAD; i += 256) cnt_s[i] = 0;
    __syncthreads();

    // pass 1: count destinations per bucket
    const int base4 = k * (EPC / 4);          // 12500 int4 per chunk
    for (int i = t; i < EPC / 4; i += 256) {
        int4 d = dst4[base4 + i];
        atomicAdd(&cnt_s[d.x >> 6], 1);
        atomicAdd(&cnt_s[d.y >> 6], 1);
        atomicAdd(&cnt_s[d.z >> 6], 1);
        atomicAdd(&cnt_s[d.w >> 6], 1);
    }
    __syncthreads();

    // in-LDS exclusive scan over SCAN_PAD values; thread t owns [t*7, t*7+7)
    int loc[7];
    int sum = 0;
    #pragma unroll
    for (int j = 0; j < 7; ++j) { loc[j] = cnt_s[t * 7 + j]; sum += loc[j]; }
    const int lane = t & 63, w = t >> 6;
    int incl = sum;
    #pragma unroll
    for (int dd = 1; dd < 64; dd <<= 1) {
        int u = __shfl_up(incl, dd, 64);
        if (lane >= dd) incl += u;
    }
    if (lane == 63) wsum_s[w] = incl;
    __syncthreads();
    int wo = 0;
    for (int ww = 0; ww < w; ++ww) wo += wsum_s[ww];
    int run = wo + incl - sum;                // exclusive prefix for thread t
    #pragma unroll
    for (int j = 0; j < 7; ++j) { cur_s[t * 7 + j] = run; run += loc[j]; }
    __syncthreads();

    // metadata (b-major for consumer-coalesced reads) while cursors are fresh
    const int rbase = k * EPC;
    for (int b = t; b < NBUK; b += 256) {
        bgstart[b * NCHUNK + k] = rbase + cur_s[b];
        bgcnt[b * NCHUNK + k]   = cnt_s[b];
    }

    // pass 2: scatter records via LDS cursors (dst re-read is L2-hot)
    for (int i = t; i < EPC / 4; i += 256) {
        int4 d = dst4[base4 + i];
        const int e = (base4 + i) * 4;
        int p;
        p = atomicAdd(&cur_s[d.x >> 6], 1); records[rbase + p] = (e)     | ((d.x & 63) << 21);
        p = atomicAdd(&cur_s[d.y >> 6], 1); records[rbase + p] = (e + 1) | ((d.y & 63) << 21);
        p = atomicAdd(&cur_s[d.z >> 6], 1); records[rbase + p] = (e + 2) | ((d.z & 63) << 21);
        p = atomicAdd(&cur_s[d.w >> 6], 1); records[rbase + p] = (e + 3) | ((d.w & 63) << 21);
    }
}

// K2: one block per bucket (64 nodes). Accumulate relu(x_src + e) into LDS
// acc[64][32] via ds-atomics (lane o -> bank o, conflict-free), then fused
// eps-update + 32x32 linear + coalesced store.
__global__ __launch_bounds__(256) void consume_kernel(
    const float* __restrict__ node, const float* __restrict__ edge,
    const int* __restrict__ src, const int* __restrict__ records,
    const int* __restrict__ bgstart, const int* __restrict__ bgcnt,
    const float* __restrict__ W, const float* __restrict__ bvec,
    const float* __restrict__ eps, float* __restrict__ out)
{
    __shared__ float Ws[D][D + 1];
    __shared__ float bs[D];
    __shared__ float acc[NPB][D];
    __shared__ int ps[NCHUNK], pc[NCHUNK];
    const int t = threadIdx.x;
    const int b = blockIdx.x;

    for (int i = t; i < D * D; i += 256) Ws[i >> 5][i & 31] = W[i];
    if (t < D) bs[t] = bvec[t];
    if (t < NCHUNK) { ps[t] = bgstart[b * NCHUNK + t]; pc[t] = bgcnt[b * NCHUNK + t]; }
    for (int i = t; i < NPB * D; i += 256) (&acc[0][0])[i] = 0.0f;
    __syncthreads();

    const int g = t >> 5;                     // group 0..7 (32 lanes each)
    const int o = t & 31;                     // feature index

    for (int pi = g; pi < NCHUNK; pi += 8) {
        const int start = ps[pi], n = pc[pi];
        for (int c = 0; c < n; c += 32) {
            const int m = min(32, n - c);
            int rec_l = 0, s_l = 0;
            if (o < m) {
                rec_l = records[start + c + o];          // coalesced
                s_l = src[rec_l & 0x1FFFFF];             // 4B gather (L2/L3-hot)
            }
            for (int j = 0; j < m; j += 8) {
                float ev[8], nv[8]; int nl[8];
                #pragma unroll
                for (int u = 0; u < 8; ++u) {
                    const int jj = j + u;
                    const int lsrc = (jj < m) ? jj : (m - 1);   // clamp to valid
                    const int r = __shfl(rec_l, lsrc, 32);
                    const int s = __shfl(s_l, lsrc, 32);
                    nl[u] = r >> 21;
                    ev[u] = edge[(long long)(r & 0x1FFFFF) * D + o];
                    nv[u] = node[(long long)s * D + o];
                }
                #pragma unroll
                for (int u = 0; u < 8; ++u) {
                    if (j + u < m)
                        atomicAdd(&acc[nl[u]][o], fmaxf(ev[u] + nv[u], 0.0f));
                }
            }
        }
    }
    __syncthreads();

    const float scale = 1.0f + eps[0];
    #pragma unroll
    for (int it = 0; it < 8; ++it) {
        const int n_l = it * 8 + g;
        const int gn = b * NPB + n_l;
        if (gn < N_NODES) {                   // uniform within the 32-lane group
            const float h = scale * node[(long long)gn * D + o] + acc[n_l][o];
            float r = bs[o];
            #pragma unroll
            for (int kk = 0; kk < D; ++kk) r += __shfl(h, kk, 32) * Ws[o][kk];
            out[(long long)gn * D + o] = r;
        }
    }
}

extern "C" void kernel_launch(void* const* d_in, const int* in_sizes, int n_in,
                              void* d_out, int out_size, void* d_ws, size_t ws_size,
                              hipStream_t stream) {
    const float* node = (const float*)d_in[0];
    const float* edge = (const float*)d_in[1];
    const int*   src  = (const int*)d_in[2];
    const int*   dst  = (const int*)d_in[3];
    const float* W    = (const float*)d_in[4];
    const float* b    = (const float*)d_in[5];
    const float* eps  = (const float*)d_in[6];
    float* out = (float*)d_out;

    // Workspace: records[E] | bgstart[NBUK*NCHUNK] | bgcnt[NBUK*NCHUNK]  (~6.8 MB)
    int* records = (int*)d_ws;
    int* bgstart = records + N_EDGES;
    int* bgcnt   = bgstart + NBUK * NCHUNK;

    build_kernel<<<NCHUNK, 256, 0, stream>>>((const int4*)dst, records, bgstart, bgcnt);
    consume_kernel<<<NBUK, 256, 0, stream>>>(node, edge, src, records, bgstart, bgcnt,
                                             W, b, eps, out);
}

// Round 6
// 155.897 us; speedup vs baseline: 2.6711x; 2.6711x over previous
//
#include <hip/hip_runtime.h>

constexpr int N_NODES = 100000;
constexpr int N_EDGES = 1600000;
constexpr int D = 32;
constexpr int NPB = 256;                            // nodes per bucket
constexpr int NBUK = (N_NODES + NPB - 1) / NPB;     // 391 buckets
constexpr int NCHUNK = 64;                          // edge chunks (hist/scatter blocks)
constexpr int EPC = N_EDGES / NCHUNK;               // 25000 edges per chunk (exact)
constexpr int MAXPT = 32;                           // max records/thread in finalize
                                                    // (32*256=8192 vs mean 4092, sigma 64)

// K1: per-chunk LDS histogram over buckets -> bgcnt[bucket][chunk].
__global__ __launch_bounds__(256) void hist_kernel(const int4* __restrict__ dst4,
                                                   int* __restrict__ bgcnt) {
    __shared__ int cnt_s[512];
    const int k = blockIdx.x, t = threadIdx.x;
    cnt_s[t] = 0; cnt_s[t + 256] = 0;
    __syncthreads();
    const int base4 = k * (EPC / 4);
    for (int i = t; i < EPC / 4; i += 256) {
        int4 d = dst4[base4 + i];
        atomicAdd(&cnt_s[d.x >> 8], 1);
        atomicAdd(&cnt_s[d.y >> 8], 1);
        atomicAdd(&cnt_s[d.z >> 8], 1);
        atomicAdd(&cnt_s[d.w >> 8], 1);
    }
    __syncthreads();
    for (int b = t; b < NBUK; b += 256) bgcnt[b * NCHUNK + k] = cnt_s[b];
}

// K2: per-bucket chunk prefix + bucket exclusive scan -> gstart[b][k], boff[b].
__global__ __launch_bounds__(512) void offsets_kernel(const int* __restrict__ bgcnt,
                                                      int* __restrict__ gstart,
                                                      int* __restrict__ boff) {
    __shared__ int part[512];
    const int t = threadIdx.x;
    int tot = 0;
    if (t < NBUK) {
        int run = 0;
        for (int k = 0; k < NCHUNK; ++k) {
            gstart[t * NCHUNK + k] = run;
            run += bgcnt[t * NCHUNK + k];
        }
        tot = run;
    }
    part[t] = tot;
    __syncthreads();
    for (int d = 1; d < 512; d <<= 1) {
        int u = (t >= d) ? part[t - d] : 0;
        __syncthreads();
        part[t] += u;
        __syncthreads();
    }
    const int my_off = part[t] - tot;     // exclusive bucket offset
    if (t < NBUK) {
        boff[t] = my_off;
        for (int k = 0; k < NCHUNK; ++k) gstart[t * NCHUNK + k] += my_off;
    }
}

// K3: scatter packed records (e | local<<21) to bucket-major order.
// Each (bucket,chunk) stripe is contiguous and written by exactly one block.
__global__ __launch_bounds__(256) void scatter_kernel(const int4* __restrict__ dst4,
                                                      const int* __restrict__ gstart,
                                                      int* __restrict__ records) {
    __shared__ int cur_s[512];
    const int k = blockIdx.x, t = threadIdx.x;
    for (int b = t; b < 512; b += 256) cur_s[b] = (b < NBUK) ? gstart[b * NCHUNK + k] : 0;
    __syncthreads();
    const int base4 = k * (EPC / 4);
    for (int i = t; i < EPC / 4; i += 256) {
        int4 d = dst4[base4 + i];
        const int e = (base4 + i) * 4;
        int p;
        p = atomicAdd(&cur_s[d.x >> 8], 1); records[p] = e       | ((d.x & 255) << 21);
        p = atomicAdd(&cur_s[d.y >> 8], 1); records[p] = (e + 1) | ((d.y & 255) << 21);
        p = atomicAdd(&cur_s[d.z >> 8], 1); records[p] = (e + 2) | ((d.z & 255) << 21);
        p = atomicAdd(&cur_s[d.w >> 8], 1); records[p] = (e + 3) | ((d.w & 255) << 21);
    }
}

// K4: one block per bucket. Buffer the bucket's records in registers (static
// indices only), LDS hist+scan of 256 local nodes -> offcnt, then rewrite the
// SAME contiguous region in-place as node-sorted CSR eid (block-exclusive).
__global__ __launch_bounds__(256) void finalize_kernel(int* __restrict__ records,
                                                       const int* __restrict__ boff,
                                                       int2* __restrict__ offcnt) {
    __shared__ int cnt_s[NPB];
    __shared__ int cur_s[NPB];
    __shared__ int wsum_s[4];
    const int b = blockIdx.x, t = threadIdx.x;
    const int s0 = boff[b];
    const int tot = ((b + 1 < NBUK) ? boff[b + 1] : N_EDGES) - s0;
    cnt_s[t] = 0;
    __syncthreads();

    int held[MAXPT];
    #pragma unroll
    for (int r = 0; r < MAXPT; ++r) {
        const int i = t + r * 256;
        held[r] = (i < tot) ? records[s0 + i] : -1;
        if (held[r] >= 0) atomicAdd(&cnt_s[held[r] >> 21], 1);
    }
    __syncthreads();

    // exclusive scan of cnt_s[256]
    const int lane = t & 63, w = t >> 6;
    const int v = cnt_s[t];
    int incl = v;
    #pragma unroll
    for (int dd = 1; dd < 64; dd <<= 1) {
        int u = __shfl_up(incl, dd, 64);
        if (lane >= dd) incl += u;
    }
    if (lane == 63) wsum_s[w] = incl;
    __syncthreads();
    int wo = 0;
    for (int ww = 0; ww < w; ++ww) wo += wsum_s[ww];
    const int excl = s0 + wo + incl - v;      // global CSR offset
    cur_s[t] = excl;
    const int gn = b * NPB + t;
    if (gn < N_NODES) offcnt[gn] = make_int2(excl, v);
    __syncthreads();

    #pragma unroll
    for (int r = 0; r < MAXPT; ++r) {
        if (held[r] >= 0) {
            const int pos = atomicAdd(&cur_s[held[r] >> 21], 1);
            records[pos] = held[r] & 0x1FFFFF;   // now plain edge id
        }
    }
}

// K5: per-node gather-sum + eps-update + 32x32 linear. 32 lanes per node,
// cooperative index prefetch, 16-edge batches (32 independent loads in flight).
__global__ __launch_bounds__(256) void gather_node_kernel(
    const float* __restrict__ node, const float* __restrict__ edge,
    const int* __restrict__ src, const int2* __restrict__ offcnt,
    const int* __restrict__ eid,
    const float* __restrict__ W, const float* __restrict__ bvec,
    const float* __restrict__ eps, float* __restrict__ out)
{
    __shared__ float Ws[D][D + 1];
    __shared__ float bs[D];
    const int t = threadIdx.x;
    for (int i = t; i < D * D; i += 256) Ws[i >> 5][i & 31] = W[i];
    if (t < D) bs[t] = bvec[t];
    __syncthreads();

    const int g = t >> 5;
    const int o = t & 31;
    const int nodeid = blockIdx.x * 8 + g;
    if (nodeid >= N_NODES) return;

    const int2 oc = offcnt[nodeid];
    const int start = oc.x;
    const int n = oc.y;
    float acc = 0.0f;

    for (int c = 0; c < n; c += 32) {
        const int m = min(32, n - c);
        int e_l = 0, s_l = 0;
        if (o < m) {
            e_l = eid[start + c + o];          // coalesced
            s_l = src[e_l];                    // 4B gather (L2/L3-hot)
        }
        for (int j = 0; j < m; j += 16) {
            float ev[16], nv[16];
            #pragma unroll
            for (int u = 0; u < 16; ++u) {
                const int jj = j + u;
                const int ls = (jj < m) ? jj : (m - 1);   // clamp: valid dup row
                const int e = __shfl(e_l, ls, 32);
                const int s = __shfl(s_l, ls, 32);
                ev[u] = edge[(long long)e * D + o];
                nv[u] = node[(long long)s * D + o];
            }
            #pragma unroll
            for (int u = 0; u < 16; ++u)
                if (j + u < m) acc += fmaxf(ev[u] + nv[u], 0.0f);
        }
    }

    const float scale = 1.0f + eps[0];
    const float h = scale * node[(long long)nodeid * D + o] + acc;

    float r = bs[o];
    #pragma unroll
    for (int kk = 0; kk < D; ++kk) r += __shfl(h, kk, 32) * Ws[o][kk];
    out[(long long)nodeid * D + o] = r;
}

extern "C" void kernel_launch(void* const* d_in, const int* in_sizes, int n_in,
                              void* d_out, int out_size, void* d_ws, size_t ws_size,
                              hipStream_t stream) {
    const float* node = (const float*)d_in[0];
    const float* edge = (const float*)d_in[1];
    const int*   src  = (const int*)d_in[2];
    const int*   dst  = (const int*)d_in[3];
    const float* W    = (const float*)d_in[4];
    const float* b    = (const float*)d_in[5];
    const float* eps  = (const float*)d_in[6];
    float* out = (float*)d_out;

    // Workspace: records[E] | bgcnt[NBUK*NCHUNK] | gstart[NBUK*NCHUNK] |
    //            boff[NBUK] | offcnt(int2)[N]   (~7.3 MB total)
    int*  records = (int*)d_ws;
    int*  bgcnt   = records + N_EDGES;
    int*  gstart  = bgcnt + NBUK * NCHUNK;
    int*  boff    = gstart + NBUK * NCHUNK;
    int2* offcnt  = (int2*)(boff + NBUK);

    hist_kernel<<<NCHUNK, 256, 0, stream>>>((const int4*)dst, bgcnt);
    offsets_kernel<<<1, 512, 0, stream>>>(bgcnt, gstart, boff);
    scatter_kernel<<<NCHUNK, 256, 0, stream>>>((const int4*)dst, gstart, records);
    finalize_kernel<<<NBUK, 256, 0, stream>>>(records, boff, offcnt);

    const int nb = (N_NODES + 7) / 8;
    gather_node_kernel<<<nb, 256, 0, stream>>>(node, edge, src, offcnt, records,
                                               W, b, eps, out);
}